// Round 2
// baseline (576.639 us; speedup 1.0000x reference)
//
#include <hip/hip_runtime.h>

typedef __bf16 bf16;
typedef __attribute__((ext_vector_type(8))) __bf16 bf16x8;
typedef __attribute__((ext_vector_type(4))) float f32x4;

// ============= convert+transpose (fp32 [R][C] -> bf16 [C][R]) =============
__global__ __launch_bounds__(256)
void transpose_f32_bf16(const float* __restrict__ src, bf16* __restrict__ dst, int R, int C)
{
  __shared__ bf16 tile[32][33];
  const int tx = threadIdx.x & 31, ty = threadIdx.x >> 5;
  const int c0 = blockIdx.x * 32, r0 = blockIdx.y * 32;
#pragma unroll
  for (int i = 0; i < 4; ++i)
    tile[ty + i * 8][tx] = (bf16)src[(size_t)(r0 + ty + i * 8) * C + c0 + tx];
  __syncthreads();
#pragma unroll
  for (int i = 0; i < 4; ++i)
    dst[(size_t)(c0 + ty + i * 8) * R + r0 + tx] = tile[tx][ty + i * 8];
}

// ============= layernorm: fp32 in -> bf16 out (one wave per 1024-col row) =============
__global__ __launch_bounds__(256)
void ln_f32_bf16(const float* __restrict__ x, const float* __restrict__ g,
                 const float* __restrict__ bta, bf16* __restrict__ out)
{
  const int row = blockIdx.x * 4 + (threadIdx.x >> 6);
  const int l = threadIdx.x & 63;
  const float* xr = x + (size_t)row * 1024 + l * 16;
  f32x4 a[4];
#pragma unroll
  for (int i = 0; i < 4; ++i) a[i] = ((const f32x4*)xr)[i];
  float s = 0.f, s2 = 0.f;
#pragma unroll
  for (int i = 0; i < 4; ++i)
#pragma unroll
    for (int jj = 0; jj < 4; ++jj) { float vv = a[i][jj]; s += vv; s2 += vv * vv; }
#pragma unroll
  for (int m = 1; m < 64; m <<= 1) { s += __shfl_xor(s, m); s2 += __shfl_xor(s2, m); }
  const float mu = s * (1.0f / 1024.0f);
  const float var = s2 * (1.0f / 1024.0f) - mu * mu;
  const float rs = rsqrtf(var + 1e-5f);
  f32x4 gv[4], bv[4];
#pragma unroll
  for (int i = 0; i < 4; ++i) {
    gv[i] = ((const f32x4*)(g + l * 16))[i];
    bv[i] = ((const f32x4*)(bta + l * 16))[i];
  }
  bf16x8 o0, o1;
#pragma unroll
  for (int i = 0; i < 8; ++i) {
    float v0 = a[i >> 2][i & 3];
    float v1 = a[2 + (i >> 2)][i & 3];
    o0[i] = (bf16)((v0 - mu) * rs * gv[i >> 2][i & 3] + bv[i >> 2][i & 3]);
    o1[i] = (bf16)((v1 - mu) * rs * gv[2 + (i >> 2)][i & 3] + bv[2 + (i >> 2)][i & 3]);
  }
  bf16* orow = out + (size_t)row * 1024 + l * 16;
  ((bf16x8*)orow)[0] = o0;
  ((bf16x8*)orow)[1] = o1;
}

// ======== GEMM: C[M,N] = A[M,K] @ Bt[N,K]^T (+fp32 bias, epilogue) ========
// EPI: 1 = bf16 q/k layout [B,H,T,hd]; 2 = bf16 v layout [B,H,hd,T];
//      3 = fp32 out = acc + bias + fp32 residual (proj);
//      4 = bf16 out = gelu(acc + bias);
//      5 = fp32 out = acc + bias + fp32 residual (final).
template <int EPI>
__global__ __launch_bounds__(256)
void gemm_bt(const bf16* __restrict__ A, const bf16* __restrict__ Bt,
             const float* __restrict__ bias, void* __restrict__ out,
             const float* __restrict__ res, int M, int N, int K)
{
  __shared__ bf16 As[128 * 40];   // [128 rows][32 data + 8 pad]
  __shared__ bf16 Bs[128 * 40];
  const int tid = threadIdx.x;
  const int l = tid & 63;
  const int w = tid >> 6;
  const int wm = w >> 1, wn = w & 1;
  const int m0 = blockIdx.x * 128;
  const int n0 = blockIdx.y * 128;

  const int r0 = tid >> 2;          // staging row (0..63), +64 for second pass
  const int s0 = (tid & 3) * 8;     // staging k-slot (elements)

  const bf16* ga0 = A + (size_t)(m0 + r0) * K + s0;
  const bf16* ga1 = A + (size_t)(m0 + 64 + r0) * K + s0;
  const bf16* gb0 = Bt + (size_t)(n0 + r0) * K + s0;
  const bf16* gb1 = Bt + (size_t)(n0 + 64 + r0) * K + s0;

  f32x4 acc[4][4] = {};
  bf16x8 ra0 = *(const bf16x8*)ga0;
  bf16x8 ra1 = *(const bf16x8*)ga1;
  bf16x8 rb0 = *(const bf16x8*)gb0;
  bf16x8 rb1 = *(const bf16x8*)gb1;

  const int KT = K >> 5;
  const int lrow = l & 15;
  const int lslot = (l >> 4) * 8;

  for (int kt = 0; kt < KT; ++kt) {
    __syncthreads();
    *(bf16x8*)&As[(r0)      * 40 + s0] = ra0;
    *(bf16x8*)&As[(r0 + 64) * 40 + s0] = ra1;
    *(bf16x8*)&Bs[(r0)      * 40 + s0] = rb0;
    *(bf16x8*)&Bs[(r0 + 64) * 40 + s0] = rb1;
    __syncthreads();
    if (kt + 1 < KT) {
      const int ko = (kt + 1) * 32;
      ra0 = *(const bf16x8*)(ga0 + ko);
      ra1 = *(const bf16x8*)(ga1 + ko);
      rb0 = *(const bf16x8*)(gb0 + ko);
      rb1 = *(const bf16x8*)(gb1 + ko);
    }
    bf16x8 af[4], bfv[4];
#pragma unroll
    for (int i = 0; i < 4; ++i)
      af[i] = *(const bf16x8*)&As[(wm * 64 + i * 16 + lrow) * 40 + lslot];
#pragma unroll
    for (int i = 0; i < 4; ++i)
      bfv[i] = *(const bf16x8*)&Bs[(wn * 64 + i * 16 + lrow) * 40 + lslot];
#pragma unroll
    for (int mi = 0; mi < 4; ++mi)
#pragma unroll
      for (int ni = 0; ni < 4; ++ni)
        acc[mi][ni] = __builtin_amdgcn_mfma_f32_16x16x32_bf16(af[mi], bfv[ni], acc[mi][ni], 0, 0, 0);
  }

  // epilogue: C/D layout col = lane&15, row = (lane>>4)*4 + j   [m89-verified]
#pragma unroll
  for (int mi = 0; mi < 4; ++mi) {
#pragma unroll
    for (int ni = 0; ni < 4; ++ni) {
      const int col = n0 + wn * 64 + ni * 16 + (l & 15);
      const float bv = bias[col];
#pragma unroll
      for (int j = 0; j < 4; ++j) {
        const int row = m0 + wm * 64 + mi * 16 + (l >> 4) * 4 + j;
        float val = acc[mi][ni][j] + bv;
        if constexpr (EPI == 1) {
          const int b = row >> 11, t = row & 2047, hh = col >> 6, d = col & 63;
          ((bf16*)out)[(((size_t)(b * 16 + hh) * 2048 + t) * 64) + d] = (bf16)val;
        } else if constexpr (EPI == 2) {
          const int b = row >> 11, t = row & 2047, hh = col >> 6, d = col & 63;
          ((bf16*)out)[(((size_t)(b * 16 + hh) * 64 + d) * 2048) + t] = (bf16)val;
        } else if constexpr (EPI == 3) {
          ((float*)out)[(size_t)row * 1024 + col] = val + res[(size_t)row * 1024 + col];
        } else if constexpr (EPI == 4) {
          const float ge = 0.5f * val * (1.0f + erff(val * 0.70710678118f));
          ((bf16*)out)[(size_t)row * N + col] = (bf16)ge;
        } else if constexpr (EPI == 5) {
          ((float*)out)[(size_t)row * 1024 + col] = val + res[(size_t)row * 1024 + col];
        }
      }
    }
  }
}

// ======================= flash attention (hybrid mask) =======================
// q,k: [B,H,T,64] bf16; v: [B,H,64,T] bf16; y out: [B,T,1024] bf16
__global__ __launch_bounds__(256)
void attn_kernel(const bf16* __restrict__ q, const bf16* __restrict__ k,
                 const bf16* __restrict__ v, bf16* __restrict__ y,
                 const int* __restrict__ condp)
{
  __shared__ bf16 Ks[64 * 72];       // [t][d] + pad8
  __shared__ bf16 Vs[64 * 72];       // [d][t] + pad8
  __shared__ bf16 Ps[4][16 * 72];    // per-wave P [q][t] + pad8
  const int tid = threadIdx.x, l = tid & 63, w = tid >> 6;
  const int qt = blockIdx.x, bh = blockIdx.y;
  const int bb = bh >> 4, hh = bh & 15;
  const int cond = condp[0];
  const int iLo = qt * 64, iHi = iLo + 63;
  const size_t base = (size_t)bh * 2048 * 64;   // same stride for q,k and v

  const int lrow = l & 15;
  const int lslot = (l >> 4) * 8;

  // Q fragments (A-layout: row = lane&15, k = (lane>>4)*8 + j)
  const int qrow = iLo + w * 16 + lrow;
  bf16x8 aq0 = *(const bf16x8*)(q + base + (size_t)qrow * 64 + lslot);
  bf16x8 aq1 = *(const bf16x8*)(q + base + (size_t)qrow * 64 + 32 + lslot);

  f32x4 o[4] = {};
  float mrow[4] = { -1e30f, -1e30f, -1e30f, -1e30f };
  float lsum[4] = { 0.f, 0.f, 0.f, 0.f };

  const int ckt = (cond + 63) >> 6;
  int nkt = (iHi >= cond) ? ((iHi >> 6) + 1) : ckt;
  if (nkt < ckt) nkt = ckt;

  const int kr = tid >> 3;            // staging row 0..31 (+32)
  const int ks8 = (tid & 7) * 8;      // staging slot (elements)

  for (int kt = 0; kt < nkt; ++kt) {
    const int j0 = kt << 6;
    *(bf16x8*)&Ks[(kr)      * 72 + ks8] = *(const bf16x8*)(k + base + (size_t)(j0 + kr) * 64 + ks8);
    *(bf16x8*)&Ks[(kr + 32) * 72 + ks8] = *(const bf16x8*)(k + base + (size_t)(j0 + kr + 32) * 64 + ks8);
    *(bf16x8*)&Vs[(kr)      * 72 + ks8] = *(const bf16x8*)(v + base + (size_t)(kr)      * 2048 + j0 + ks8);
    *(bf16x8*)&Vs[(kr + 32) * 72 + ks8] = *(const bf16x8*)(v + base + (size_t)(kr + 32) * 2048 + j0 + ks8);
    __syncthreads();

    // S = Q @ K^T
    f32x4 sfr[4];
#pragma unroll
    for (int nf = 0; nf < 4; ++nf) {
      f32x4 s = {};
      bf16x8 kb0 = *(const bf16x8*)&Ks[(nf * 16 + lrow) * 72 + lslot];
      bf16x8 kb1 = *(const bf16x8*)&Ks[(nf * 16 + lrow) * 72 + 32 + lslot];
      s = __builtin_amdgcn_mfma_f32_16x16x32_bf16(aq0, kb0, s, 0, 0, 0);
      s = __builtin_amdgcn_mfma_f32_16x16x32_bf16(aq1, kb1, s, 0, 0, 0);
      const int jc = j0 + nf * 16 + (l & 15);
#pragma unroll
      for (int j = 0; j < 4; ++j) {
        const int irow = iLo + w * 16 + (l >> 4) * 4 + j;
        const float sv = s[j] * 0.125f;
        const bool ok = (jc < cond) || (jc <= irow);
        s[j] = ok ? sv : -1e30f;
      }
      sfr[nf] = s;
    }

    // online softmax per row (16-lane row-groups)
    float alpha[4];
#pragma unroll
    for (int j = 0; j < 4; ++j) {
      float mm = fmaxf(fmaxf(sfr[0][j], sfr[1][j]), fmaxf(sfr[2][j], sfr[3][j]));
      mm = fmaxf(mm, __shfl_xor(mm, 1));
      mm = fmaxf(mm, __shfl_xor(mm, 2));
      mm = fmaxf(mm, __shfl_xor(mm, 4));
      mm = fmaxf(mm, __shfl_xor(mm, 8));
      const float mnew = fmaxf(mrow[j], mm);
      alpha[j] = __expf(mrow[j] - mnew);
      mrow[j] = mnew;
      float rs = 0.f;
#pragma unroll
      for (int nf = 0; nf < 4; ++nf) {
        const float pv = __expf(sfr[nf][j] - mnew);
        sfr[nf][j] = pv;
        rs += pv;
      }
      rs += __shfl_xor(rs, 1);
      rs += __shfl_xor(rs, 2);
      rs += __shfl_xor(rs, 4);
      rs += __shfl_xor(rs, 8);
      lsum[j] = lsum[j] * alpha[j] + rs;
    }

    // P (C-layout) -> LDS -> A-layout
#pragma unroll
    for (int nf = 0; nf < 4; ++nf)
#pragma unroll
      for (int j = 0; j < 4; ++j)
        Ps[w][((l >> 4) * 4 + j) * 72 + nf * 16 + (l & 15)] = (bf16)sfr[nf][j];
    __syncthreads();

    bf16x8 pa0 = *(const bf16x8*)&Ps[w][lrow * 72 + lslot];
    bf16x8 pa1 = *(const bf16x8*)&Ps[w][lrow * 72 + 32 + lslot];
#pragma unroll
    for (int df = 0; df < 4; ++df) {
      f32x4 oo = o[df];
#pragma unroll
      for (int j = 0; j < 4; ++j) oo[j] *= alpha[j];
      bf16x8 v0 = *(const bf16x8*)&Vs[(df * 16 + lrow) * 72 + lslot];
      bf16x8 v1 = *(const bf16x8*)&Vs[(df * 16 + lrow) * 72 + 32 + lslot];
      oo = __builtin_amdgcn_mfma_f32_16x16x32_bf16(pa0, v0, oo, 0, 0, 0);
      oo = __builtin_amdgcn_mfma_f32_16x16x32_bf16(pa1, v1, oo, 0, 0, 0);
      o[df] = oo;
    }
    __syncthreads();   // protect Ks/Vs before next stage
  }

  // epilogue: y[b, t, h*64 + d] (bf16)
#pragma unroll
  for (int df = 0; df < 4; ++df)
#pragma unroll
    for (int j = 0; j < 4; ++j) {
      const int irow = iLo + w * 16 + (l >> 4) * 4 + j;
      const float val = o[df][j] / lsum[j];
      y[((size_t)bb * 2048 + irow) * 1024 + hh * 64 + df * 16 + (l & 15)] = (bf16)val;
    }
}

// ======================= launcher =======================
extern "C" void kernel_launch(void* const* d_in, const int* in_sizes, int n_in,
                              void* d_out, int out_size, void* d_ws, size_t ws_size,
                              hipStream_t stream) {
  const float* x    = (const float*)d_in[0];
  const float* ln1g = (const float*)d_in[1];
  const float* ln1b = (const float*)d_in[2];
  const float* Wk   = (const float*)d_in[3];
  const float* bk   = (const float*)d_in[4];
  const float* Wq   = (const float*)d_in[5];
  const float* bq   = (const float*)d_in[6];
  const float* Wv   = (const float*)d_in[7];
  const float* bv   = (const float*)d_in[8];
  const float* Wp   = (const float*)d_in[9];
  const float* bpb  = (const float*)d_in[10];
  const float* ln2g = (const float*)d_in[11];
  const float* ln2b = (const float*)d_in[12];
  const float* W1   = (const float*)d_in[13];
  const float* b1   = (const float*)d_in[14];
  const float* W2   = (const float*)d_in[15];
  const float* b2   = (const float*)d_in[16];
  const int*  cond  = (const int*)d_in[17];
  float* out = (float*)d_out;

  char* ws = (char*)d_ws;
  const size_t MB = 1024ull * 1024ull;
  if (ws_size < 136 * MB) return;   // need 136 MB scratch

  bf16*  WqT  = (bf16*)(ws + 0 * MB);
  bf16*  WkT  = (bf16*)(ws + 2 * MB);
  bf16*  WvT  = (bf16*)(ws + 4 * MB);
  bf16*  WpT  = (bf16*)(ws + 6 * MB);
  bf16*  W1T  = (bf16*)(ws + 8 * MB);   // [4096][1024] bf16 = 8 MB
  bf16*  W2T  = (bf16*)(ws + 16 * MB);  // [1024][4096] bf16 = 8 MB
  float* x2   = (float*)(ws + 24 * MB); // fp32 [8192][1024] = 32 MB
  bf16*  hbuf = (bf16*)(ws + 56 * MB);  // bf16 [8192][1024] = 16 MB
  bf16*  qb   = (bf16*)(ws + 72 * MB);
  bf16*  kb   = (bf16*)(ws + 88 * MB);
  bf16*  vb   = (bf16*)(ws + 104 * MB);
  bf16*  yb   = (bf16*)(ws + 120 * MB);
  bf16*  m1   = (bf16*)(ws + 72 * MB);  // [8192][4096] bf16 = 64 MB, reuses q/k/v/y

  dim3 blk(256);
  transpose_f32_bf16<<<dim3(32, 32), blk, 0, stream>>>(Wq, WqT, 1024, 1024);
  transpose_f32_bf16<<<dim3(32, 32), blk, 0, stream>>>(Wk, WkT, 1024, 1024);
  transpose_f32_bf16<<<dim3(32, 32), blk, 0, stream>>>(Wv, WvT, 1024, 1024);
  transpose_f32_bf16<<<dim3(32, 32), blk, 0, stream>>>(Wp, WpT, 1024, 1024);
  transpose_f32_bf16<<<dim3(128, 32), blk, 0, stream>>>(W1, W1T, 1024, 4096);
  transpose_f32_bf16<<<dim3(32, 128), blk, 0, stream>>>(W2, W2T, 4096, 1024);

  ln_f32_bf16<<<2048, blk, 0, stream>>>(x, ln1g, ln1b, hbuf);

  gemm_bt<1><<<dim3(64, 8), blk, 0, stream>>>(hbuf, WqT, bq, qb, nullptr, 8192, 1024, 1024);
  gemm_bt<1><<<dim3(64, 8), blk, 0, stream>>>(hbuf, WkT, bk, kb, nullptr, 8192, 1024, 1024);
  gemm_bt<2><<<dim3(64, 8), blk, 0, stream>>>(hbuf, WvT, bv, vb, nullptr, 8192, 1024, 1024);

  attn_kernel<<<dim3(32, 64), blk, 0, stream>>>(qb, kb, vb, yb, cond);

  gemm_bt<3><<<dim3(64, 8), blk, 0, stream>>>(yb, WpT, bpb, x2, x, 8192, 1024, 1024);
  ln_f32_bf16<<<2048, blk, 0, stream>>>(x2, ln2g, ln2b, hbuf);
  gemm_bt<4><<<dim3(64, 32), blk, 0, stream>>>(hbuf, W1T, b1, m1, nullptr, 8192, 4096, 1024);
  gemm_bt<5><<<dim3(64, 8), blk, 0, stream>>>(m1, W2T, b2, out, x2, 8192, 1024, 4096);
}

// Round 3
// 555.112 us; speedup vs baseline: 1.0388x; 1.0388x over previous
//
#include <hip/hip_runtime.h>

typedef __bf16 bf16;
typedef __attribute__((ext_vector_type(8))) __bf16 bf16x8;
typedef __attribute__((ext_vector_type(4))) float f32x4;

// ============= convert+transpose (fp32 [R][C] -> bf16 [C][R]) =============
__global__ __launch_bounds__(256)
void transpose_f32_bf16(const float* __restrict__ src, bf16* __restrict__ dst, int R, int C)
{
  __shared__ bf16 tile[32][33];
  const int tx = threadIdx.x & 31, ty = threadIdx.x >> 5;
  const int c0 = blockIdx.x * 32, r0 = blockIdx.y * 32;
#pragma unroll
  for (int i = 0; i < 4; ++i)
    tile[ty + i * 8][tx] = (bf16)src[(size_t)(r0 + ty + i * 8) * C + c0 + tx];
  __syncthreads();
#pragma unroll
  for (int i = 0; i < 4; ++i)
    dst[(size_t)(c0 + ty + i * 8) * R + r0 + tx] = tile[tx][ty + i * 8];
}

// ============= layernorm: fp32 in -> bf16 out (one wave per 1024-col row) =============
__global__ __launch_bounds__(256)
void ln_f32_bf16(const float* __restrict__ x, const float* __restrict__ g,
                 const float* __restrict__ bta, bf16* __restrict__ out)
{
  const int row = blockIdx.x * 4 + (threadIdx.x >> 6);
  const int l = threadIdx.x & 63;
  const float* xr = x + (size_t)row * 1024 + l * 16;
  f32x4 a[4];
#pragma unroll
  for (int i = 0; i < 4; ++i) a[i] = ((const f32x4*)xr)[i];
  float s = 0.f, s2 = 0.f;
#pragma unroll
  for (int i = 0; i < 4; ++i)
#pragma unroll
    for (int jj = 0; jj < 4; ++jj) { float vv = a[i][jj]; s += vv; s2 += vv * vv; }
#pragma unroll
  for (int m = 1; m < 64; m <<= 1) { s += __shfl_xor(s, m); s2 += __shfl_xor(s2, m); }
  const float mu = s * (1.0f / 1024.0f);
  const float var = s2 * (1.0f / 1024.0f) - mu * mu;
  const float rs = rsqrtf(var + 1e-5f);
  f32x4 gv[4], bv[4];
#pragma unroll
  for (int i = 0; i < 4; ++i) {
    gv[i] = ((const f32x4*)(g + l * 16))[i];
    bv[i] = ((const f32x4*)(bta + l * 16))[i];
  }
  bf16x8 o0, o1;
#pragma unroll
  for (int i = 0; i < 8; ++i) {
    float v0 = a[i >> 2][i & 3];
    float v1 = a[2 + (i >> 2)][i & 3];
    o0[i] = (bf16)((v0 - mu) * rs * gv[i >> 2][i & 3] + bv[i >> 2][i & 3]);
    o1[i] = (bf16)((v1 - mu) * rs * gv[2 + (i >> 2)][i & 3] + bv[2 + (i >> 2)][i & 3]);
  }
  bf16* orow = out + (size_t)row * 1024 + l * 16;
  ((bf16x8*)orow)[0] = o0;
  ((bf16x8*)orow)[1] = o1;
}

// ======== GEMM: C[M,N] = A[M,K] @ Bt[N,K]^T (+fp32 bias, epilogue) ========
// EPI: 1 = bf16 q/k layout [B,H,T,hd]; 2 = bf16 v layout [B,H,hd,T];
//      3 = fp32 out = acc + bias + fp32 residual (proj);
//      4 = bf16 out = gelu(acc + bias);
//      5 = fp32 out = acc + bias + fp32 residual (final).
template <int EPI>
__global__ __launch_bounds__(256)
void gemm_bt(const bf16* __restrict__ A, const bf16* __restrict__ Bt,
             const float* __restrict__ bias, void* __restrict__ out,
             const float* __restrict__ res, int M, int N, int K)
{
  __shared__ bf16 As[128 * 40];   // [128 rows][32 data + 8 pad]
  __shared__ bf16 Bs[128 * 40];
  const int tid = threadIdx.x;
  const int l = tid & 63;
  const int w = tid >> 6;
  const int wm = w >> 1, wn = w & 1;
  const int m0 = blockIdx.x * 128;
  const int n0 = blockIdx.y * 128;

  const int r0 = tid >> 2;          // staging row (0..63), +64 for second pass
  const int s0 = (tid & 3) * 8;     // staging k-slot (elements)

  const bf16* ga0 = A + (size_t)(m0 + r0) * K + s0;
  const bf16* ga1 = A + (size_t)(m0 + 64 + r0) * K + s0;
  const bf16* gb0 = Bt + (size_t)(n0 + r0) * K + s0;
  const bf16* gb1 = Bt + (size_t)(n0 + 64 + r0) * K + s0;

  f32x4 acc[4][4] = {};
  bf16x8 ra0 = *(const bf16x8*)ga0;
  bf16x8 ra1 = *(const bf16x8*)ga1;
  bf16x8 rb0 = *(const bf16x8*)gb0;
  bf16x8 rb1 = *(const bf16x8*)gb1;

  const int KT = K >> 5;
  const int lrow = l & 15;
  const int lslot = (l >> 4) * 8;

  for (int kt = 0; kt < KT; ++kt) {
    __syncthreads();
    *(bf16x8*)&As[(r0)      * 40 + s0] = ra0;
    *(bf16x8*)&As[(r0 + 64) * 40 + s0] = ra1;
    *(bf16x8*)&Bs[(r0)      * 40 + s0] = rb0;
    *(bf16x8*)&Bs[(r0 + 64) * 40 + s0] = rb1;
    __syncthreads();
    if (kt + 1 < KT) {
      const int ko = (kt + 1) * 32;
      ra0 = *(const bf16x8*)(ga0 + ko);
      ra1 = *(const bf16x8*)(ga1 + ko);
      rb0 = *(const bf16x8*)(gb0 + ko);
      rb1 = *(const bf16x8*)(gb1 + ko);
    }
    bf16x8 af[4], bfv[4];
#pragma unroll
    for (int i = 0; i < 4; ++i)
      af[i] = *(const bf16x8*)&As[(wm * 64 + i * 16 + lrow) * 40 + lslot];
#pragma unroll
    for (int i = 0; i < 4; ++i)
      bfv[i] = *(const bf16x8*)&Bs[(wn * 64 + i * 16 + lrow) * 40 + lslot];
#pragma unroll
    for (int mi = 0; mi < 4; ++mi)
#pragma unroll
      for (int ni = 0; ni < 4; ++ni)
        acc[mi][ni] = __builtin_amdgcn_mfma_f32_16x16x32_bf16(af[mi], bfv[ni], acc[mi][ni], 0, 0, 0);
  }

  // epilogue: C/D layout col = lane&15, row = (lane>>4)*4 + j   [m89-verified]
#pragma unroll
  for (int mi = 0; mi < 4; ++mi) {
#pragma unroll
    for (int ni = 0; ni < 4; ++ni) {
      const int col = n0 + wn * 64 + ni * 16 + (l & 15);
      const float bv = bias[col];
#pragma unroll
      for (int j = 0; j < 4; ++j) {
        const int row = m0 + wm * 64 + mi * 16 + (l >> 4) * 4 + j;
        float val = acc[mi][ni][j] + bv;
        if constexpr (EPI == 1) {
          const int b = row >> 11, t = row & 2047, hh = col >> 6, d = col & 63;
          ((bf16*)out)[(((size_t)(b * 16 + hh) * 2048 + t) * 64) + d] = (bf16)val;
        } else if constexpr (EPI == 2) {
          const int b = row >> 11, t = row & 2047, hh = col >> 6, d = col & 63;
          ((bf16*)out)[(((size_t)(b * 16 + hh) * 64 + d) * 2048) + t] = (bf16)val;
        } else if constexpr (EPI == 3) {
          ((float*)out)[(size_t)row * 1024 + col] = val + res[(size_t)row * 1024 + col];
        } else if constexpr (EPI == 4) {
          const float ge = 0.5f * val * (1.0f + erff(val * 0.70710678118f));
          ((bf16*)out)[(size_t)row * N + col] = (bf16)ge;
        } else if constexpr (EPI == 5) {
          ((float*)out)[(size_t)row * 1024 + col] = val + res[(size_t)row * 1024 + col];
        }
      }
    }
  }
}

// ======================= flash attention (hybrid mask), 8-wave QBLK=128 =======================
// q,k: [B,H,T,64] bf16; v: [B,H,64,T] bf16; y out: [B,T,1024] bf16
// Double-buffered K/V in LDS, one __syncthreads per K-tile; prefetch-early/write-late.
__global__ __launch_bounds__(512)
void attn_kernel(const bf16* __restrict__ q, const bf16* __restrict__ k,
                 const bf16* __restrict__ v, bf16* __restrict__ y,
                 const int* __restrict__ condp)
{
  __shared__ bf16 Ks[2][64 * 72];    // [t][d] + pad8
  __shared__ bf16 Vs[2][64 * 72];    // [d][t] + pad8
  __shared__ bf16 Ps[8][16 * 72];    // per-wave P [q][t] + pad8
  const int tid = threadIdx.x, l = tid & 63, w = tid >> 6;
  const int qt = 15 - blockIdx.x;    // long blocks dispatch first (load balance)
  const int bh = blockIdx.y;
  const int bb = bh >> 4, hh = bh & 15;
  const int cond = condp[0];
  const int iLo = qt * 128, iHi = iLo + 127;
  const size_t base = (size_t)bh * 2048 * 64;   // same stride for q,k and v

  const int lrow = l & 15;
  const int lslot = (l >> 4) * 8;

  // Q fragments (A-layout: row = lane&15, k = (lane>>4)*8 + j)
  const int qrow = iLo + w * 16 + lrow;
  bf16x8 aq0 = *(const bf16x8*)(q + base + (size_t)qrow * 64 + lslot);
  bf16x8 aq1 = *(const bf16x8*)(q + base + (size_t)qrow * 64 + 32 + lslot);

  f32x4 o[4] = {};
  float mrow[4] = { -1e30f, -1e30f, -1e30f, -1e30f };
  float lsum[4] = { 0.f, 0.f, 0.f, 0.f };

  const int ckt = (cond + 63) >> 6;
  int nkt = (iHi >> 6) + 1;
  if (nkt < ckt) nkt = ckt;

  // staging: 512 threads cover a full 64x64 bf16 tile with one bf16x8 each
  const int kr = tid >> 3;            // 0..63
  const int ks8 = (tid & 7) * 8;      // 0..56
  const bf16* kp = k + base + (size_t)kr * 64 + ks8;    // + j0*64 per tile
  const bf16* vp = v + base + (size_t)kr * 2048 + ks8;  // + j0 per tile

  bf16x8 rk = *(const bf16x8*)kp;
  bf16x8 rv = *(const bf16x8*)vp;
  *(bf16x8*)&Ks[0][kr * 72 + ks8] = rk;
  *(bf16x8*)&Vs[0][kr * 72 + ks8] = rv;
  __syncthreads();

  for (int kt = 0; kt < nkt; ++kt) {
    const int cur = kt & 1;
    const int j0 = kt << 6;
    const bool pf = (kt + 1 < nkt);
    if (pf) {   // issue next-tile global loads early; latency hides under compute
      rk = *(const bf16x8*)(kp + (size_t)(j0 + 64) * 64);
      rv = *(const bf16x8*)(vp + j0 + 64);
    }

    // S = Q @ K^T
    f32x4 sfr[4];
    __builtin_amdgcn_s_setprio(1);
#pragma unroll
    for (int nf = 0; nf < 4; ++nf) {
      f32x4 s = {};
      bf16x8 kb0 = *(const bf16x8*)&Ks[cur][(nf * 16 + lrow) * 72 + lslot];
      bf16x8 kb1 = *(const bf16x8*)&Ks[cur][(nf * 16 + lrow) * 72 + 32 + lslot];
      s = __builtin_amdgcn_mfma_f32_16x16x32_bf16(aq0, kb0, s, 0, 0, 0);
      s = __builtin_amdgcn_mfma_f32_16x16x32_bf16(aq1, kb1, s, 0, 0, 0);
      sfr[nf] = s;
    }
    __builtin_amdgcn_s_setprio(0);

    // mask + scale
#pragma unroll
    for (int nf = 0; nf < 4; ++nf) {
      const int jc = j0 + nf * 16 + (l & 15);
#pragma unroll
      for (int j = 0; j < 4; ++j) {
        const int irow = iLo + w * 16 + (l >> 4) * 4 + j;
        const float sv = sfr[nf][j] * 0.125f;
        const bool ok = (jc < cond) || (jc <= irow);
        sfr[nf][j] = ok ? sv : -1e30f;
      }
    }

    // online softmax per row (16-lane row-groups)
    float alpha[4];
#pragma unroll
    for (int j = 0; j < 4; ++j) {
      float mm = fmaxf(fmaxf(sfr[0][j], sfr[1][j]), fmaxf(sfr[2][j], sfr[3][j]));
      mm = fmaxf(mm, __shfl_xor(mm, 1));
      mm = fmaxf(mm, __shfl_xor(mm, 2));
      mm = fmaxf(mm, __shfl_xor(mm, 4));
      mm = fmaxf(mm, __shfl_xor(mm, 8));
      const float mnew = fmaxf(mrow[j], mm);
      alpha[j] = __expf(mrow[j] - mnew);
      mrow[j] = mnew;
      float rs = 0.f;
#pragma unroll
      for (int nf = 0; nf < 4; ++nf) {
        const float pv = __expf(sfr[nf][j] - mnew);
        sfr[nf][j] = pv;
        rs += pv;
      }
      rs += __shfl_xor(rs, 1);
      rs += __shfl_xor(rs, 2);
      rs += __shfl_xor(rs, 4);
      rs += __shfl_xor(rs, 8);
      lsum[j] = lsum[j] * alpha[j] + rs;
    }

    // P (C-layout) -> LDS -> A-layout (wave-local, no barrier needed)
#pragma unroll
    for (int nf = 0; nf < 4; ++nf)
#pragma unroll
      for (int j = 0; j < 4; ++j)
        Ps[w][((l >> 4) * 4 + j) * 72 + nf * 16 + (l & 15)] = (bf16)sfr[nf][j];

    bf16x8 pa0 = *(const bf16x8*)&Ps[w][lrow * 72 + lslot];
    bf16x8 pa1 = *(const bf16x8*)&Ps[w][lrow * 72 + 32 + lslot];
    __builtin_amdgcn_s_setprio(1);
#pragma unroll
    for (int df = 0; df < 4; ++df) {
      f32x4 oo = o[df];
#pragma unroll
      for (int j = 0; j < 4; ++j) oo[j] *= alpha[j];
      bf16x8 v0 = *(const bf16x8*)&Vs[cur][(df * 16 + lrow) * 72 + lslot];
      bf16x8 v1 = *(const bf16x8*)&Vs[cur][(df * 16 + lrow) * 72 + 32 + lslot];
      oo = __builtin_amdgcn_mfma_f32_16x16x32_bf16(pa0, v0, oo, 0, 0, 0);
      oo = __builtin_amdgcn_mfma_f32_16x16x32_bf16(pa1, v1, oo, 0, 0, 0);
      o[df] = oo;
    }
    __builtin_amdgcn_s_setprio(0);

    if (pf) {   // write next tile into the other buffer (read side done)
      *(bf16x8*)&Ks[cur ^ 1][kr * 72 + ks8] = rk;
      *(bf16x8*)&Vs[cur ^ 1][kr * 72 + ks8] = rv;
    }
    __syncthreads();
  }

  // epilogue: y[b, t, h*64 + d] (bf16)
#pragma unroll
  for (int df = 0; df < 4; ++df)
#pragma unroll
    for (int j = 0; j < 4; ++j) {
      const int irow = iLo + w * 16 + (l >> 4) * 4 + j;
      const float val = o[df][j] / lsum[j];
      y[((size_t)bb * 2048 + irow) * 1024 + hh * 64 + df * 16 + (l & 15)] = (bf16)val;
    }
}

// ======================= launcher =======================
extern "C" void kernel_launch(void* const* d_in, const int* in_sizes, int n_in,
                              void* d_out, int out_size, void* d_ws, size_t ws_size,
                              hipStream_t stream) {
  const float* x    = (const float*)d_in[0];
  const float* ln1g = (const float*)d_in[1];
  const float* ln1b = (const float*)d_in[2];
  const float* Wk   = (const float*)d_in[3];
  const float* bk   = (const float*)d_in[4];
  const float* Wq   = (const float*)d_in[5];
  const float* bq   = (const float*)d_in[6];
  const float* Wv   = (const float*)d_in[7];
  const float* bv   = (const float*)d_in[8];
  const float* Wp   = (const float*)d_in[9];
  const float* bpb  = (const float*)d_in[10];
  const float* ln2g = (const float*)d_in[11];
  const float* ln2b = (const float*)d_in[12];
  const float* W1   = (const float*)d_in[13];
  const float* b1   = (const float*)d_in[14];
  const float* W2   = (const float*)d_in[15];
  const float* b2   = (const float*)d_in[16];
  const int*  cond  = (const int*)d_in[17];
  float* out = (float*)d_out;

  char* ws = (char*)d_ws;
  const size_t MB = 1024ull * 1024ull;
  if (ws_size < 136 * MB) return;   // need 136 MB scratch

  bf16*  WqT  = (bf16*)(ws + 0 * MB);
  bf16*  WkT  = (bf16*)(ws + 2 * MB);
  bf16*  WvT  = (bf16*)(ws + 4 * MB);
  bf16*  WpT  = (bf16*)(ws + 6 * MB);
  bf16*  W1T  = (bf16*)(ws + 8 * MB);   // [4096][1024] bf16 = 8 MB
  bf16*  W2T  = (bf16*)(ws + 16 * MB);  // [1024][4096] bf16 = 8 MB
  float* x2   = (float*)(ws + 24 * MB); // fp32 [8192][1024] = 32 MB
  bf16*  hbuf = (bf16*)(ws + 56 * MB);  // bf16 [8192][1024] = 16 MB
  bf16*  qb   = (bf16*)(ws + 72 * MB);
  bf16*  kb   = (bf16*)(ws + 88 * MB);
  bf16*  vb   = (bf16*)(ws + 104 * MB);
  bf16*  yb   = (bf16*)(ws + 120 * MB);
  bf16*  m1   = (bf16*)(ws + 72 * MB);  // [8192][4096] bf16 = 64 MB, reuses q/k/v/y

  dim3 blk(256);
  transpose_f32_bf16<<<dim3(32, 32), blk, 0, stream>>>(Wq, WqT, 1024, 1024);
  transpose_f32_bf16<<<dim3(32, 32), blk, 0, stream>>>(Wk, WkT, 1024, 1024);
  transpose_f32_bf16<<<dim3(32, 32), blk, 0, stream>>>(Wv, WvT, 1024, 1024);
  transpose_f32_bf16<<<dim3(32, 32), blk, 0, stream>>>(Wp, WpT, 1024, 1024);
  transpose_f32_bf16<<<dim3(128, 32), blk, 0, stream>>>(W1, W1T, 1024, 4096);
  transpose_f32_bf16<<<dim3(32, 128), blk, 0, stream>>>(W2, W2T, 4096, 1024);

  ln_f32_bf16<<<2048, blk, 0, stream>>>(x, ln1g, ln1b, hbuf);

  gemm_bt<1><<<dim3(64, 8), blk, 0, stream>>>(hbuf, WqT, bq, qb, nullptr, 8192, 1024, 1024);
  gemm_bt<1><<<dim3(64, 8), blk, 0, stream>>>(hbuf, WkT, bk, kb, nullptr, 8192, 1024, 1024);
  gemm_bt<2><<<dim3(64, 8), blk, 0, stream>>>(hbuf, WvT, bv, vb, nullptr, 8192, 1024, 1024);

  attn_kernel<<<dim3(16, 64), dim3(512), 0, stream>>>(qb, kb, vb, yb, cond);

  gemm_bt<3><<<dim3(64, 8), blk, 0, stream>>>(yb, WpT, bpb, x2, x, 8192, 1024, 1024);
  ln_f32_bf16<<<2048, blk, 0, stream>>>(x2, ln2g, ln2b, hbuf);
  gemm_bt<4><<<dim3(64, 32), blk, 0, stream>>>(hbuf, W1T, b1, m1, nullptr, 8192, 4096, 1024);
  gemm_bt<5><<<dim3(64, 8), blk, 0, stream>>>(m1, W2T, b2, out, x2, 8192, 1024, 4096);
}

// Round 4
// 418.541 us; speedup vs baseline: 1.3777x; 1.3263x over previous
//
#include <hip/hip_runtime.h>

typedef __bf16 bf16;
typedef __attribute__((ext_vector_type(4))) __bf16 bf16x4;
typedef __attribute__((ext_vector_type(8))) __bf16 bf16x8;
typedef __attribute__((ext_vector_type(4))) float f32x4;

// ============= convert+transpose (fp32 [R][C] -> bf16 [C][R]) =============
__global__ __launch_bounds__(256)
void transpose_f32_bf16(const float* __restrict__ src, bf16* __restrict__ dst, int R, int C)
{
  __shared__ bf16 tile[32][33];
  const int tx = threadIdx.x & 31, ty = threadIdx.x >> 5;
  const int c0 = blockIdx.x * 32, r0 = blockIdx.y * 32;
#pragma unroll
  for (int i = 0; i < 4; ++i)
    tile[ty + i * 8][tx] = (bf16)src[(size_t)(r0 + ty + i * 8) * C + c0 + tx];
  __syncthreads();
#pragma unroll
  for (int i = 0; i < 4; ++i)
    dst[(size_t)(c0 + ty + i * 8) * R + r0 + tx] = tile[tx][ty + i * 8];
}

// ============= layernorm: fp32 in -> bf16 out (one wave per 1024-col row) =============
__global__ __launch_bounds__(256)
void ln_f32_bf16(const float* __restrict__ x, const float* __restrict__ g,
                 const float* __restrict__ bta, bf16* __restrict__ out)
{
  const int row = blockIdx.x * 4 + (threadIdx.x >> 6);
  const int l = threadIdx.x & 63;
  const float* xr = x + (size_t)row * 1024 + l * 16;
  f32x4 a[4];
#pragma unroll
  for (int i = 0; i < 4; ++i) a[i] = ((const f32x4*)xr)[i];
  float s = 0.f, s2 = 0.f;
#pragma unroll
  for (int i = 0; i < 4; ++i)
#pragma unroll
    for (int jj = 0; jj < 4; ++jj) { float vv = a[i][jj]; s += vv; s2 += vv * vv; }
#pragma unroll
  for (int m = 1; m < 64; m <<= 1) { s += __shfl_xor(s, m); s2 += __shfl_xor(s2, m); }
  const float mu = s * (1.0f / 1024.0f);
  const float var = s2 * (1.0f / 1024.0f) - mu * mu;
  const float rs = rsqrtf(var + 1e-5f);
  f32x4 gv[4], bv[4];
#pragma unroll
  for (int i = 0; i < 4; ++i) {
    gv[i] = ((const f32x4*)(g + l * 16))[i];
    bv[i] = ((const f32x4*)(bta + l * 16))[i];
  }
  bf16x8 o0, o1;
#pragma unroll
  for (int i = 0; i < 8; ++i) {
    float v0 = a[i >> 2][i & 3];
    float v1 = a[2 + (i >> 2)][i & 3];
    o0[i] = (bf16)((v0 - mu) * rs * gv[i >> 2][i & 3] + bv[i >> 2][i & 3]);
    o1[i] = (bf16)((v1 - mu) * rs * gv[2 + (i >> 2)][i & 3] + bv[2 + (i >> 2)][i & 3]);
  }
  bf16* orow = out + (size_t)row * 1024 + l * 16;
  ((bf16x8*)orow)[0] = o0;
  ((bf16x8*)orow)[1] = o1;
}

// ======== GEMM: C[M,N] = A[M,K] @ Bt[N,K]^T (+fp32 bias, epilogue) ========
// EPI: 1 = bf16 q/k layout [B,H,T,hd] (scaled by oscale); 2 = bf16 v layout [B,H,hd,T];
//      3 = fp32 out = acc + bias + fp32 residual (proj);
//      4 = bf16 out = gelu(acc + bias);
//      5 = fp32 out = acc + bias + fp32 residual (final).
template <int EPI>
__global__ __launch_bounds__(256)
void gemm_bt(const bf16* __restrict__ A, const bf16* __restrict__ Bt,
             const float* __restrict__ bias, void* __restrict__ out,
             const float* __restrict__ res, int M, int N, int K, float oscale)
{
  __shared__ bf16 As[128 * 40];   // [128 rows][32 data + 8 pad]
  __shared__ bf16 Bs[128 * 40];
  const int tid = threadIdx.x;
  const int l = tid & 63;
  const int w = tid >> 6;
  const int wm = w >> 1, wn = w & 1;
  const int m0 = blockIdx.x * 128;
  const int n0 = blockIdx.y * 128;

  const int r0 = tid >> 2;
  const int s0 = (tid & 3) * 8;

  const bf16* ga0 = A + (size_t)(m0 + r0) * K + s0;
  const bf16* ga1 = A + (size_t)(m0 + 64 + r0) * K + s0;
  const bf16* gb0 = Bt + (size_t)(n0 + r0) * K + s0;
  const bf16* gb1 = Bt + (size_t)(n0 + 64 + r0) * K + s0;

  f32x4 acc[4][4] = {};
  bf16x8 ra0 = *(const bf16x8*)ga0;
  bf16x8 ra1 = *(const bf16x8*)ga1;
  bf16x8 rb0 = *(const bf16x8*)gb0;
  bf16x8 rb1 = *(const bf16x8*)gb1;

  const int KT = K >> 5;
  const int lrow = l & 15;
  const int lslot = (l >> 4) * 8;

  for (int kt = 0; kt < KT; ++kt) {
    __syncthreads();
    *(bf16x8*)&As[(r0)      * 40 + s0] = ra0;
    *(bf16x8*)&As[(r0 + 64) * 40 + s0] = ra1;
    *(bf16x8*)&Bs[(r0)      * 40 + s0] = rb0;
    *(bf16x8*)&Bs[(r0 + 64) * 40 + s0] = rb1;
    __syncthreads();
    if (kt + 1 < KT) {
      const int ko = (kt + 1) * 32;
      ra0 = *(const bf16x8*)(ga0 + ko);
      ra1 = *(const bf16x8*)(ga1 + ko);
      rb0 = *(const bf16x8*)(gb0 + ko);
      rb1 = *(const bf16x8*)(gb1 + ko);
    }
    bf16x8 af[4], bfv[4];
#pragma unroll
    for (int i = 0; i < 4; ++i)
      af[i] = *(const bf16x8*)&As[(wm * 64 + i * 16 + lrow) * 40 + lslot];
#pragma unroll
    for (int i = 0; i < 4; ++i)
      bfv[i] = *(const bf16x8*)&Bs[(wn * 64 + i * 16 + lrow) * 40 + lslot];
#pragma unroll
    for (int mi = 0; mi < 4; ++mi)
#pragma unroll
      for (int ni = 0; ni < 4; ++ni)
        acc[mi][ni] = __builtin_amdgcn_mfma_f32_16x16x32_bf16(af[mi], bfv[ni], acc[mi][ni], 0, 0, 0);
  }

#pragma unroll
  for (int mi = 0; mi < 4; ++mi) {
#pragma unroll
    for (int ni = 0; ni < 4; ++ni) {
      const int col = n0 + wn * 64 + ni * 16 + (l & 15);
      const float bv = bias[col];
#pragma unroll
      for (int j = 0; j < 4; ++j) {
        const int row = m0 + wm * 64 + mi * 16 + (l >> 4) * 4 + j;
        float val = acc[mi][ni][j] + bv;
        if constexpr (EPI == 1) {
          const int b = row >> 11, t = row & 2047, hh = col >> 6, d = col & 63;
          ((bf16*)out)[(((size_t)(b * 16 + hh) * 2048 + t) * 64) + d] = (bf16)(val * oscale);
        } else if constexpr (EPI == 2) {
          const int b = row >> 11, t = row & 2047, hh = col >> 6, d = col & 63;
          ((bf16*)out)[(((size_t)(b * 16 + hh) * 64 + d) * 2048) + t] = (bf16)val;
        } else if constexpr (EPI == 3) {
          ((float*)out)[(size_t)row * 1024 + col] = val + res[(size_t)row * 1024 + col];
        } else if constexpr (EPI == 4) {
          const float ge = 0.5f * val * (1.0f + erff(val * 0.70710678118f));
          ((bf16*)out)[(size_t)row * N + col] = (bf16)ge;
        } else if constexpr (EPI == 5) {
          ((float*)out)[(size_t)row * 1024 + col] = val + res[(size_t)row * 1024 + col];
        }
      }
    }
  }
}

// ======================= flash attention, swapped-QK^T + defer-max =======================
// q: [B,H,T,64] bf16 PRE-SCALED by 1/8; k: [B,H,T,64]; v: [B,H,64,T]; y: [B,T,1024] bf16
__global__ __launch_bounds__(512)
void attn_kernel(const bf16* __restrict__ q, const bf16* __restrict__ k,
                 const bf16* __restrict__ v, bf16* __restrict__ y,
                 const int* __restrict__ condp)
{
  __shared__ bf16 Ks[2][64 * 72];    // [t][d], stride 72 elem (144B, 16B-aligned)
  __shared__ bf16 Vs[2][64 * 72];    // [d][t]
  __shared__ char PsB[8][2048];      // per-wave P [16 q][64 k] bf16, XOR-swizzled 16B slots
  const int tid = threadIdx.x, l = tid & 63, w = tid >> 6;
  const int bx = blockIdx.x;
  const int qt = 15 - (bx >> 6);     // global qt-descending: heavy blocks dispatch first
  const int bh = bx & 63;
  const int bb = bh >> 4, hh = bh & 15;
  const int cond = condp[0];
  const int iLo = qt * 128;
  const size_t base = (size_t)bh * 2048 * 64;

  const int lrow = l & 15;           // q-row within wave (for S/P), d within df (for O)
  const int g = l >> 4;
  const int lslot = g * 8;

  // Q as B-operand: col=lane&15 -> q-row, k-dim=d=(lane>>4)*8+j
  const int qrow = iLo + w * 16 + lrow;
  const bf16x8 bq0 = *(const bf16x8*)(q + base + (size_t)qrow * 64 + lslot);
  const bf16x8 bq1 = *(const bf16x8*)(q + base + (size_t)qrow * 64 + 32 + lslot);

  f32x4 o[4] = {};
  float m = -1e30f, lsum = 0.f;      // softmax state for q-row (l&15) of this wave

  const int ckt = (cond + 63) >> 6;
  int nkt = ((iLo + 127) >> 6) + 1;
  if (nkt < ckt) nkt = ckt;
  const int wHi = iLo + w * 16 + 15; // this wave's max q-row

  // staging: 512 threads cover one 64x64 bf16 tile with one bf16x8 each
  const int kr = tid >> 3;
  const int ks8 = (tid & 7) * 8;
  const bf16* kp = k + base + (size_t)kr * 64 + ks8;
  const bf16* vp = v + base + (size_t)kr * 2048 + ks8;

  bf16x8 rk = *(const bf16x8*)kp;
  bf16x8 rv = *(const bf16x8*)vp;
  *(bf16x8*)&Ks[0][kr * 72 + ks8] = rk;
  *(bf16x8*)&Vs[0][kr * 72 + ks8] = rv;
  __syncthreads();

  char* psw = PsB[w];

  for (int kt = 0; kt < nkt; ++kt) {
    const int cur = kt & 1;
    const int j0 = kt << 6;
    const bool pf = (kt + 1 < nkt);
    if (pf) {
      rk = *(const bf16x8*)(kp + (size_t)(j0 + 64) * 64);
      rv = *(const bf16x8*)(vp + j0 + 64);
    }

    const bool active = (j0 < cond) || (j0 <= wHi);
    if (active) {
      // S^T = K @ Q : C col = lane&15 = q, C row = (lane>>4)*4+j = k-local
      f32x4 sfr[4];
      __builtin_amdgcn_s_setprio(1);
#pragma unroll
      for (int nf = 0; nf < 4; ++nf) {
        f32x4 s = {};
        bf16x8 ka0 = *(const bf16x8*)&Ks[cur][(nf * 16 + lrow) * 72 + lslot];
        bf16x8 ka1 = *(const bf16x8*)&Ks[cur][(nf * 16 + lrow) * 72 + 32 + lslot];
        s = __builtin_amdgcn_mfma_f32_16x16x32_bf16(ka0, bq0, s, 0, 0, 0);
        s = __builtin_amdgcn_mfma_f32_16x16x32_bf16(ka1, bq1, s, 0, 0, 0);
        sfr[nf] = s;
      }
      __builtin_amdgcn_s_setprio(0);

      // mask only when not wave-uniformly safe
      const bool safe = (j0 + 63 < cond) || (j0 + 63 <= iLo + w * 16);
      if (!safe) {
#pragma unroll
        for (int nf = 0; nf < 4; ++nf)
#pragma unroll
          for (int j = 0; j < 4; ++j) {
            const int kc = j0 + nf * 16 + g * 4 + j;
            const bool ok = (kc < cond) || (kc <= qrow);
            sfr[nf][j] = ok ? sfr[nf][j] : -1e30f;
          }
      }

      // row max: 15 in-lane + 2 shfl
      float pmax = sfr[0][0];
#pragma unroll
      for (int nf = 0; nf < 4; ++nf)
#pragma unroll
        for (int j = 0; j < 4; ++j) pmax = fmaxf(pmax, sfr[nf][j]);
      pmax = fmaxf(pmax, __shfl_xor(pmax, 16));
      pmax = fmaxf(pmax, __shfl_xor(pmax, 32));

      // defer-max: rescale only when max grew by > 8
      const bool resc = !__all(pmax - m <= 8.0f);
      if (resc) {
        const float mnew = fmaxf(m, pmax);
        const float alpha = __expf(m - mnew);
        m = mnew;
        lsum *= alpha;
        // redistribute alpha to this lane's O rows (r = 4g+j lives on lane 20g+j... (l&48)|r)
        float ar[4];
#pragma unroll
        for (int j = 0; j < 4; ++j) ar[j] = __shfl(alpha, (l & 48) | (g * 4 + j));
#pragma unroll
        for (int df = 0; df < 4; ++df)
#pragma unroll
          for (int j = 0; j < 4; ++j) o[df][j] *= ar[j];
      }

      // P = exp(S - m), row-sum, pack 4 bf16 -> one b64 LDS store per nf
      float rsum = 0.f;
#pragma unroll
      for (int nf = 0; nf < 4; ++nf) {
        bf16x4 pk;
#pragma unroll
        for (int j = 0; j < 4; ++j) {
          const float p = __expf(sfr[nf][j] - m);
          rsum += p;
          pk[j] = (bf16)p;
        }
        // write P[q=lrow][k=nf*16+g*4 .. +3]; 16B-slot XOR swizzle with q&7
        const int slot = 2 * nf + (g >> 1);
        const int boff = lrow * 128 + ((slot ^ (lrow & 7)) << 4) + (g & 1) * 8;
        *(bf16x4*)(psw + boff) = pk;
      }
      rsum += __shfl_xor(rsum, 16);
      rsum += __shfl_xor(rsum, 32);
      lsum += rsum;

      // PV: A = P[q][k], B = V[k][d] from Vs[d][t]
      const int r0b = lrow * 128 + (((g    ) ^ (lrow & 7)) << 4);
      const int r1b = lrow * 128 + (((g + 4) ^ (lrow & 7)) << 4);
      const bf16x8 pa0 = *(const bf16x8*)(psw + r0b);
      const bf16x8 pa1 = *(const bf16x8*)(psw + r1b);
      __builtin_amdgcn_s_setprio(1);
#pragma unroll
      for (int df = 0; df < 4; ++df) {
        bf16x8 v0 = *(const bf16x8*)&Vs[cur][(df * 16 + lrow) * 72 + lslot];
        bf16x8 v1 = *(const bf16x8*)&Vs[cur][(df * 16 + lrow) * 72 + 32 + lslot];
        o[df] = __builtin_amdgcn_mfma_f32_16x16x32_bf16(pa0, v0, o[df], 0, 0, 0);
        o[df] = __builtin_amdgcn_mfma_f32_16x16x32_bf16(pa1, v1, o[df], 0, 0, 0);
      }
      __builtin_amdgcn_s_setprio(0);
    }

    if (pf) {
      *(bf16x8*)&Ks[cur ^ 1][kr * 72 + ks8] = rk;
      *(bf16x8*)&Vs[cur ^ 1][kr * 72 + ks8] = rv;
    }
    __syncthreads();
  }

  // fetch lsum for this lane's O rows, write y[b, t, h*64 + d]
  float lr[4];
#pragma unroll
  for (int j = 0; j < 4; ++j) lr[j] = 1.0f / __shfl(lsum, (l & 48) | (g * 4 + j));
#pragma unroll
  for (int df = 0; df < 4; ++df)
#pragma unroll
    for (int j = 0; j < 4; ++j) {
      const int irow = iLo + w * 16 + g * 4 + j;
      y[((size_t)bb * 2048 + irow) * 1024 + hh * 64 + df * 16 + lrow] = (bf16)(o[df][j] * lr[j]);
    }
}

// ======================= launcher =======================
extern "C" void kernel_launch(void* const* d_in, const int* in_sizes, int n_in,
                              void* d_out, int out_size, void* d_ws, size_t ws_size,
                              hipStream_t stream) {
  const float* x    = (const float*)d_in[0];
  const float* ln1g = (const float*)d_in[1];
  const float* ln1b = (const float*)d_in[2];
  const float* Wk   = (const float*)d_in[3];
  const float* bk   = (const float*)d_in[4];
  const float* Wq   = (const float*)d_in[5];
  const float* bq   = (const float*)d_in[6];
  const float* Wv   = (const float*)d_in[7];
  const float* bv   = (const float*)d_in[8];
  const float* Wp   = (const float*)d_in[9];
  const float* bpb  = (const float*)d_in[10];
  const float* ln2g = (const float*)d_in[11];
  const float* ln2b = (const float*)d_in[12];
  const float* W1   = (const float*)d_in[13];
  const float* b1   = (const float*)d_in[14];
  const float* W2   = (const float*)d_in[15];
  const float* b2   = (const float*)d_in[16];
  const int*  cond  = (const int*)d_in[17];
  float* out = (float*)d_out;

  char* ws = (char*)d_ws;
  const size_t MB = 1024ull * 1024ull;
  if (ws_size < 136 * MB) return;

  bf16*  WqT  = (bf16*)(ws + 0 * MB);
  bf16*  WkT  = (bf16*)(ws + 2 * MB);
  bf16*  WvT  = (bf16*)(ws + 4 * MB);
  bf16*  WpT  = (bf16*)(ws + 6 * MB);
  bf16*  W1T  = (bf16*)(ws + 8 * MB);
  bf16*  W2T  = (bf16*)(ws + 16 * MB);
  float* x2   = (float*)(ws + 24 * MB);
  bf16*  hbuf = (bf16*)(ws + 56 * MB);
  bf16*  qb   = (bf16*)(ws + 72 * MB);
  bf16*  kb   = (bf16*)(ws + 88 * MB);
  bf16*  vb   = (bf16*)(ws + 104 * MB);
  bf16*  yb   = (bf16*)(ws + 120 * MB);
  bf16*  m1   = (bf16*)(ws + 72 * MB);

  dim3 blk(256);
  transpose_f32_bf16<<<dim3(32, 32), blk, 0, stream>>>(Wq, WqT, 1024, 1024);
  transpose_f32_bf16<<<dim3(32, 32), blk, 0, stream>>>(Wk, WkT, 1024, 1024);
  transpose_f32_bf16<<<dim3(32, 32), blk, 0, stream>>>(Wv, WvT, 1024, 1024);
  transpose_f32_bf16<<<dim3(32, 32), blk, 0, stream>>>(Wp, WpT, 1024, 1024);
  transpose_f32_bf16<<<dim3(128, 32), blk, 0, stream>>>(W1, W1T, 1024, 4096);
  transpose_f32_bf16<<<dim3(32, 128), blk, 0, stream>>>(W2, W2T, 4096, 1024);

  ln_f32_bf16<<<2048, blk, 0, stream>>>(x, ln1g, ln1b, hbuf);

  gemm_bt<1><<<dim3(64, 8), blk, 0, stream>>>(hbuf, WqT, bq, qb, nullptr, 8192, 1024, 1024, 0.125f);
  gemm_bt<1><<<dim3(64, 8), blk, 0, stream>>>(hbuf, WkT, bk, kb, nullptr, 8192, 1024, 1024, 1.0f);
  gemm_bt<2><<<dim3(64, 8), blk, 0, stream>>>(hbuf, WvT, bv, vb, nullptr, 8192, 1024, 1024, 1.0f);

  attn_kernel<<<dim3(1024), dim3(512), 0, stream>>>(qb, kb, vb, yb, cond);

  gemm_bt<3><<<dim3(64, 8), blk, 0, stream>>>(yb, WpT, bpb, x2, x, 8192, 1024, 1024, 1.0f);
  ln_f32_bf16<<<2048, blk, 0, stream>>>(x2, ln2g, ln2b, hbuf);
  gemm_bt<4><<<dim3(64, 32), blk, 0, stream>>>(hbuf, W1T, b1, m1, nullptr, 8192, 4096, 1024, 1.0f);
  gemm_bt<5><<<dim3(64, 8), blk, 0, stream>>>(m1, W2T, b2, out, x2, 8192, 1024, 4096, 1.0f);
}